// Round 4
// baseline (764.075 us; speedup 1.0000x reference)
//
#include <hip/hip_runtime.h>

#define VOCAB 50000
#define OOV   100
#define EXT   50100
#define UNITS 512
#define EMB   256
#define NS    32
#define NW    50
#define BATCH 64
#define NQ    8          // vocab range splits for copy-histogram kernel
#define BINS_PER ((EXT + NQ - 1) / NQ)   // 6263

__device__ __forceinline__ float sigmoidf_(float x) { return 1.f / (1.f + __expf(-x)); }

// ---------------- Kernel A: GRU step (one block per batch row) ----------------
__global__ __launch_bounds__(256) void k_gru(
    const float* __restrict__ emb, const float* __restrict__ h0,
    const float* __restrict__ Wx, const float* __restrict__ Wh,
    const float* __restrict__ gb, float* __restrict__ ws_dec,
    float* __restrict__ out_dec)
{
  __shared__ float sx[EMB];
  __shared__ float sh[UNITS];
  const int b = blockIdx.x, t = threadIdx.x;
  sx[t]       = emb[b * EMB + t];
  sh[t]       = h0[b * UNITS + t];
  sh[t + 256] = h0[b * UNITS + 256 + t];
  __syncthreads();

  const int u0 = 2 * t;
  float2 xz = *(const float2*)(gb + u0);
  float2 xr = *(const float2*)(gb + 512 + u0);
  float2 xh = *(const float2*)(gb + 1024 + u0);
  float2 hz = *(const float2*)(gb + 1536 + u0);
  float2 hr = *(const float2*)(gb + 1536 + 512 + u0);
  float2 hh = *(const float2*)(gb + 1536 + 1024 + u0);

  for (int k = 0; k < EMB; ++k) {
    const float x = sx[k];
    const float* row = Wx + k * 1536;
    const float2 wz = *(const float2*)(row + u0);
    const float2 wr = *(const float2*)(row + 512 + u0);
    const float2 wh = *(const float2*)(row + 1024 + u0);
    xz.x = fmaf(x, wz.x, xz.x); xz.y = fmaf(x, wz.y, xz.y);
    xr.x = fmaf(x, wr.x, xr.x); xr.y = fmaf(x, wr.y, xr.y);
    xh.x = fmaf(x, wh.x, xh.x); xh.y = fmaf(x, wh.y, xh.y);
  }
  for (int k = 0; k < UNITS; ++k) {
    const float h = sh[k];
    const float* row = Wh + k * 1536;
    const float2 wz = *(const float2*)(row + u0);
    const float2 wr = *(const float2*)(row + 512 + u0);
    const float2 wh = *(const float2*)(row + 1024 + u0);
    hz.x = fmaf(h, wz.x, hz.x); hz.y = fmaf(h, wz.y, hz.y);
    hr.x = fmaf(h, wr.x, hr.x); hr.y = fmaf(h, wr.y, hr.y);
    hh.x = fmaf(h, wh.x, hh.x); hh.y = fmaf(h, wh.y, hh.y);
  }

  const float hp0 = sh[u0], hp1 = sh[u0 + 1];
  const float z0 = sigmoidf_(xz.x + hz.x), z1 = sigmoidf_(xz.y + hz.y);
  const float r0 = sigmoidf_(xr.x + hr.x), r1 = sigmoidf_(xr.y + hr.y);
  const float c0 = tanhf(xh.x + r0 * hh.x), c1 = tanhf(xh.y + r1 * hh.y);
  const float n0 = z0 * hp0 + (1.f - z0) * c0;
  const float n1 = z1 * hp1 + (1.f - z1) * c1;
  ws_dec[b * UNITS + u0]     = n0;
  ws_dec[b * UNITS + u0 + 1] = n1;
  out_dec[b * UNITS + u0]     = n0;
  out_dec[b * UNITS + u0 + 1] = n1;
}

// ------- Kernel B: sentence attention + context + hidden_t + qw + p_gen -------
__global__ __launch_bounds__(256) void k_attn(
    const float* __restrict__ ws_dec,
    const float* __restrict__ Wsent, const float* __restrict__ Wword,
    const float* __restrict__ encS, const float* __restrict__ wdec,
    const float* __restrict__ wctx, const float* __restrict__ whid,
    const float* __restrict__ winp, const float* __restrict__ emb,
    float* __restrict__ ws_qw, float* __restrict__ ws_alpha,
    float* __restrict__ ws_ht, float* __restrict__ out_pgen)
{
  __shared__ float sdec[UNITS], sq[UNITS], sqw[UNITS], sctx[UNITS];
  __shared__ float sscore[NS], salpha[NS];
  __shared__ float sred[256];
  const int b = blockIdx.x, t = threadIdx.x;
  sdec[t]       = ws_dec[b * UNITS + t];
  sdec[t + 256] = ws_dec[b * UNITS + 256 + t];
  __syncthreads();

  {
    const int u0 = 2 * t;
    float q0 = 0.f, q1 = 0.f, w0 = 0.f, w1 = 0.f;
    for (int k = 0; k < UNITS; ++k) {
      const float d = sdec[k];
      const float2 a = *(const float2*)(Wsent + k * UNITS + u0);
      const float2 c = *(const float2*)(Wword + k * UNITS + u0);
      q0 = fmaf(d, a.x, q0); q1 = fmaf(d, a.y, q1);
      w0 = fmaf(d, c.x, w0); w1 = fmaf(d, c.y, w1);
    }
    sq[u0] = q0; sq[u0 + 1] = q1;
    sqw[u0] = w0; sqw[u0 + 1] = w1;
    ws_qw[b * UNITS + u0] = w0; ws_qw[b * UNITS + u0 + 1] = w1;
  }
  __syncthreads();

  const int wave = t >> 6, lane = t & 63;
  float qr[8];
#pragma unroll
  for (int j = 0; j < 8; ++j) qr[j] = sq[lane * 8 + j];
  for (int s = wave; s < NS; s += 4) {
    const float* base = encS + ((size_t)(b * NS + s)) * UNITS + lane * 8;
    const float4 v0 = *(const float4*)(base);
    const float4 v1 = *(const float4*)(base + 4);
    float acc = 0.f;
    acc = fmaf(v0.x, qr[0], acc); acc = fmaf(v0.y, qr[1], acc);
    acc = fmaf(v0.z, qr[2], acc); acc = fmaf(v0.w, qr[3], acc);
    acc = fmaf(v1.x, qr[4], acc); acc = fmaf(v1.y, qr[5], acc);
    acc = fmaf(v1.z, qr[6], acc); acc = fmaf(v1.w, qr[7], acc);
#pragma unroll
    for (int off = 32; off > 0; off >>= 1) acc += __shfl_down(acc, off);
    if (lane == 0) sscore[s] = acc;
  }
  __syncthreads();

  if (t < 32) {
    const float v = sscore[t];
    float m = v;
#pragma unroll
    for (int off = 16; off > 0; off >>= 1) m = fmaxf(m, __shfl_xor(m, off));
    const float e = __expf(v - m);
    float ssum = e;
#pragma unroll
    for (int off = 16; off > 0; off >>= 1) ssum += __shfl_xor(ssum, off);
    const float a = e / ssum;
    salpha[t] = a;
    ws_alpha[b * NS + t] = a;
  }
  __syncthreads();

  for (int u = t; u < UNITS; u += 256) {
    float c = 0.f;
    for (int s = 0; s < NS; ++s)
      c = fmaf(salpha[s], encS[((size_t)(b * NS + s)) * UNITS + u], c);
    sctx[u] = c;
  }
  __syncthreads();

  {
    float acc = 0.f;
    for (int k = 0; k < UNITS; ++k)
      acc = fmaf(sctx[k], wdec[k * 256 + t], acc);
    for (int k = 0; k < UNITS; ++k)
      acc = fmaf(sdec[k], wdec[(UNITS + k) * 256 + t], acc);
    ws_ht[b * 256 + t] = tanhf(acc);
  }

  float p = sctx[t] * wctx[t] + sctx[t + 256] * wctx[t + 256] +
            sdec[t] * whid[t] + sdec[t + 256] * whid[t + 256] +
            emb[b * EMB + t] * winp[t];
  sred[t] = p;
  __syncthreads();
  for (int off = 128; off > 0; off >>= 1) {
    if (t < off) sred[t] += sred[t + off];
    __syncthreads();
  }
  if (t == 0) out_pgen[b] = sigmoidf_(sred[0]);
}

// ---- Kernel C: gen exp(logits) -> out_gen (fp32) + fp32 rowsum atomics ----
__global__ __launch_bounds__(256) void k_fc(
    const float* __restrict__ ws_ht, const float* __restrict__ fcW,
    const float* __restrict__ fcb, float* __restrict__ out_gen,
    float* __restrict__ ws_rowsum)
{
  __shared__ float sht[EMB * 16];  // transposed [k][r]: conflict-free broadcast
  const int t = threadIdx.x;
  const int g = blockIdx.y;        // row group (16 rows)
  const int cb = blockIdx.x * 512;

#pragma unroll
  for (int i = 0; i < 16; ++i)
    sht[t * 16 + i] = ws_ht[(g * 16 + i) * EMB + t];
  __syncthreads();

  const int c0 = cb + 2 * t;
  float2 acc[16];
#pragma unroll
  for (int r = 0; r < 16; ++r) acc[r] = make_float2(0.f, 0.f);

  if (c0 < VOCAB) {
    for (int k = 0; k < EMB; ++k) {
      const float2 w = *(const float2*)(fcW + (size_t)k * VOCAB + c0);
      const float* hp = sht + k * 16;
#pragma unroll
      for (int r = 0; r < 16; ++r) {
        const float h = hp[r];
        acc[r].x = fmaf(h, w.x, acc[r].x);
        acc[r].y = fmaf(h, w.y, acc[r].y);
      }
    }
    const float2 bb = *(const float2*)(fcb + c0);
#pragma unroll
    for (int r = 0; r < 16; ++r) {
      acc[r].x = __expf(acc[r].x + bb.x);   // logits tiny; no max-shift needed
      acc[r].y = __expf(acc[r].y + bb.y);
      *(float2*)(out_gen + (size_t)(g * 16 + r) * EXT + c0) = acc[r];
    }
  }
  const int lane = t & 63;
#pragma unroll
  for (int r = 0; r < 16; ++r) {
    float s = (c0 < VOCAB) ? (acc[r].x + acc[r].y) : 0.f;
#pragma unroll
    for (int off = 32; off > 0; off >>= 1) s += __shfl_down(s, off);
    if (lane == 0) atomicAdd(ws_rowsum + g * 16 + r, s);
  }
}

// ---- Kernel D: word attention -> beta (fp32, ws), block per (b,s) ----
__global__ __launch_bounds__(256) void k_word(
    const float* __restrict__ ws_qw, const float* __restrict__ encW,
    const float* __restrict__ ws_alpha, float* __restrict__ ws_beta)
{
  __shared__ float sqw[UNITS];
  __shared__ float sscore[NW];
  const int bi = blockIdx.x;
  const int b = bi >> 5, s = bi & 31;
  const int t = threadIdx.x;
  sqw[t]       = ws_qw[b * UNITS + t];
  sqw[t + 256] = ws_qw[b * UNITS + 256 + t];
  __syncthreads();

  const int wave = t >> 6, lane = t & 63;
  float qr[8];
#pragma unroll
  for (int j = 0; j < 8; ++j) qr[j] = sqw[lane * 8 + j];
  const float* base = encW + ((size_t)(b * NS + s)) * NW * UNITS;
  for (int w = wave; w < NW; w += 4) {
    const float* row = base + w * UNITS + lane * 8;
    const float4 v0 = *(const float4*)(row);
    const float4 v1 = *(const float4*)(row + 4);
    float acc = 0.f;
    acc = fmaf(v0.x, qr[0], acc); acc = fmaf(v0.y, qr[1], acc);
    acc = fmaf(v0.z, qr[2], acc); acc = fmaf(v0.w, qr[3], acc);
    acc = fmaf(v1.x, qr[4], acc); acc = fmaf(v1.y, qr[5], acc);
    acc = fmaf(v1.z, qr[6], acc); acc = fmaf(v1.w, qr[7], acc);
#pragma unroll
    for (int off = 32; off > 0; off >>= 1) acc += __shfl_down(acc, off);
    if (lane == 0) sscore[w] = acc;
  }
  __syncthreads();

  if (t < 64) {
    const float v = (t < NW) ? sscore[t] : -1e30f;
    float m = v;
#pragma unroll
    for (int off = 32; off > 0; off >>= 1) m = fmaxf(m, __shfl_xor(m, off));
    const float e = (t < NW) ? __expf(v - m) : 0.f;
    float sum = e;
#pragma unroll
    for (int off = 32; off > 0; off >>= 1) sum += __shfl_xor(sum, off);
    if (t < NW)
      ws_beta[b * (NS * NW) + s * NW + t] = ws_alpha[b * NS + s] * e / sum;
  }
}

// ---- Kernel E: LDS-histogram scatter-add -> out_copy (block per (b, range)) --
__global__ __launch_bounds__(256) void k_copy(
    const int* __restrict__ nidx, const float* __restrict__ ws_beta,
    float* __restrict__ out_copy)
{
  __shared__ float shist[BINS_PER];
  const int q = blockIdx.x, b = blockIdx.y, t = threadIdx.x;
  const int base = q * BINS_PER;
  const int len = min(BINS_PER, EXT - base);

  for (int j = t; j < BINS_PER; j += 256) shist[j] = 0.f;
  __syncthreads();

  for (int e = t; e < NS * NW; e += 256) {
    const int rel = nidx[b * (NS * NW) + e] - base;
    if (rel >= 0 && rel < len) atomicAdd(shist + rel, ws_beta[b * (NS * NW) + e]);
  }
  __syncthreads();

  for (int j = t; j < len; j += 256)
    out_copy[(size_t)b * EXT + base + j] = shist[j];
}

// ------------- Kernel F: normalize out_gen in place + zero OOV pad -------------
__global__ __launch_bounds__(256) void k_final(
    const float* __restrict__ ws_rowsum, float* __restrict__ out_gen)
{
  const int i = blockIdx.x * 256 + threadIdx.x;
  if (i >= BATCH * EXT) return;
  const int b = i / EXT, c = i - b * EXT;
  float g = 0.f;
  if (c < VOCAB) g = out_gen[i] / ws_rowsum[b];
  out_gen[i] = g;
}

extern "C" void kernel_launch(void* const* d_in, const int* in_sizes, int n_in,
                              void* d_out, int out_size, void* d_ws, size_t ws_size,
                              hipStream_t stream)
{
  const float* emb   = (const float*)d_in[0];
  const float* h0    = (const float*)d_in[1];
  const float* encS  = (const float*)d_in[2];
  const float* encW  = (const float*)d_in[3];
  const int*   nidx  = (const int*)d_in[4];
  const float* Wx    = (const float*)d_in[6];
  const float* Wh    = (const float*)d_in[7];
  const float* gb    = (const float*)d_in[8];
  const float* Wsent = (const float*)d_in[9];
  const float* Wword = (const float*)d_in[10];
  const float* fcW   = (const float*)d_in[11];
  const float* fcb   = (const float*)d_in[12];
  const float* wctx  = (const float*)d_in[13];
  const float* whid  = (const float*)d_in[14];
  const float* wdec  = (const float*)d_in[15];
  const float* winp  = (const float*)d_in[16];

  float* ws        = (float*)d_ws;        // total ~750 KB
  float* ws_dec    = ws;                          // 64*512
  float* ws_qw     = ws_dec + BATCH * UNITS;      // 64*512
  float* ws_alpha  = ws_qw + BATCH * UNITS;       // 64*32
  float* ws_ht     = ws_alpha + BATCH * NS;       // 64*256
  float* ws_rowsum = ws_ht + BATCH * EMB;         // 64
  float* ws_beta   = ws_rowsum + BATCH;           // 64*1600

  float* out      = (float*)d_out;   // outputs are float32 per reference
  float* out_dec  = out;                                    // 64*512
  float* out_gen  = out + BATCH * UNITS;                    // 64*50100
  float* out_copy = out_gen + (size_t)BATCH * EXT;          // 64*50100
  float* out_pgen = out_copy + (size_t)BATCH * EXT;         // 64

  hipMemsetAsync(ws_rowsum, 0, BATCH * sizeof(float), stream);

  k_gru<<<BATCH, 256, 0, stream>>>(emb, h0, Wx, Wh, gb, ws_dec, out_dec);
  k_attn<<<BATCH, 256, 0, stream>>>(ws_dec, Wsent, Wword, encS, wdec, wctx,
                                    whid, winp, emb, ws_qw, ws_alpha, ws_ht,
                                    out_pgen);
  k_fc<<<dim3((VOCAB + 511) / 512, 4), 256, 0, stream>>>(ws_ht, fcW, fcb,
                                                         out_gen, ws_rowsum);
  k_word<<<BATCH * NS, 256, 0, stream>>>(ws_qw, encW, ws_alpha, ws_beta);
  k_copy<<<dim3(NQ, BATCH), 256, 0, stream>>>(nidx, ws_beta, out_copy);
  k_final<<<(BATCH * EXT + 255) / 256, 256, 0, stream>>>(ws_rowsum, out_gen);
}

// Round 5
// 660.039 us; speedup vs baseline: 1.1576x; 1.1576x over previous
//
#include <hip/hip_runtime.h>

#define VOCAB 50000
#define OOV   100
#define EXT   50100
#define UNITS 512
#define EMB   256
#define NS    32
#define NW    50
#define BATCH 64
#define NQ    8          // vocab range splits for copy-histogram kernel
#define BINS_PER ((EXT + NQ - 1) / NQ)   // 6263

#define GKC   4   // gru k-split chunks (768/4 = 192)
#define QKC   4   // q/qw k-split chunks (512/4 = 128)
#define HKC   4   // ht k-split chunks (1024/4 = 256)

__device__ __forceinline__ float sigmoidf_(float x) { return 1.f / (1.f + __expf(-x)); }

// ---- K1: GRU partial sums, k-split. grid (GKC, BATCH), 256 thr ----
// partial layout per (kc,b): [az(512) | ar(512) | ahx(512) | ahh(512)]
__global__ __launch_bounds__(256) void k_gru_part(
    const float* __restrict__ emb, const float* __restrict__ h0,
    const float* __restrict__ Wx, const float* __restrict__ Wh,
    float* __restrict__ gp)
{
  __shared__ float sv[192];
  const int kc = blockIdx.x, b = blockIdx.y, t = threadIdx.x, u0 = 2 * t;
  const int base = kc * 192;
  if (t < 192) {
    const int k = base + t;
    sv[t] = (k < EMB) ? emb[b * EMB + k] : h0[b * UNITS + (k - EMB)];
  }
  __syncthreads();

  float2 az = {0.f, 0.f}, ar = {0.f, 0.f}, ahx = {0.f, 0.f}, ahh = {0.f, 0.f};
  const int nx = min(192, max(0, EMB - base));   // x-part iterations
#pragma unroll 4
  for (int i = 0; i < nx; ++i) {
    const float x = sv[i];
    const float* row = Wx + (size_t)(base + i) * 1536;
    const float2 wz = *(const float2*)(row + u0);
    const float2 wr = *(const float2*)(row + 512 + u0);
    const float2 wh = *(const float2*)(row + 1024 + u0);
    az.x = fmaf(x, wz.x, az.x); az.y = fmaf(x, wz.y, az.y);
    ar.x = fmaf(x, wr.x, ar.x); ar.y = fmaf(x, wr.y, ar.y);
    ahx.x = fmaf(x, wh.x, ahx.x); ahx.y = fmaf(x, wh.y, ahx.y);
  }
#pragma unroll 4
  for (int i = nx; i < 192; ++i) {
    const float h = sv[i];
    const float* row = Wh + (size_t)(base + i - EMB) * 1536;
    const float2 wz = *(const float2*)(row + u0);
    const float2 wr = *(const float2*)(row + 512 + u0);
    const float2 wh = *(const float2*)(row + 1024 + u0);
    az.x = fmaf(h, wz.x, az.x); az.y = fmaf(h, wz.y, az.y);
    ar.x = fmaf(h, wr.x, ar.x); ar.y = fmaf(h, wr.y, ar.y);
    ahh.x = fmaf(h, wh.x, ahh.x); ahh.y = fmaf(h, wh.y, ahh.y);
  }
  float* o = gp + (size_t)(kc * BATCH + b) * 2048;
  *(float2*)(o + u0) = az;
  *(float2*)(o + 512 + u0) = ar;
  *(float2*)(o + 1024 + u0) = ahx;
  *(float2*)(o + 1536 + u0) = ahh;
}

// ---- K2: GRU gate finalize. grid (BATCH), 256 thr ----
__global__ __launch_bounds__(256) void k_gru_fin(
    const float* __restrict__ gp, const float* __restrict__ gb,
    const float* __restrict__ h0, float* __restrict__ ws_dec,
    float* __restrict__ out_dec)
{
  const int b = blockIdx.x, t = threadIdx.x, u0 = 2 * t;
  float2 az = {0.f, 0.f}, ar = {0.f, 0.f}, ahx = {0.f, 0.f}, ahh = {0.f, 0.f};
#pragma unroll
  for (int c = 0; c < GKC; ++c) {
    const float* o = gp + (size_t)(c * BATCH + b) * 2048;
    const float2 z = *(const float2*)(o + u0);
    const float2 r = *(const float2*)(o + 512 + u0);
    const float2 hx = *(const float2*)(o + 1024 + u0);
    const float2 hh = *(const float2*)(o + 1536 + u0);
    az.x += z.x; az.y += z.y; ar.x += r.x; ar.y += r.y;
    ahx.x += hx.x; ahx.y += hx.y; ahh.x += hh.x; ahh.y += hh.y;
  }
  const float2 b0z = *(const float2*)(gb + u0);
  const float2 b0r = *(const float2*)(gb + 512 + u0);
  const float2 b0h = *(const float2*)(gb + 1024 + u0);
  const float2 b1z = *(const float2*)(gb + 1536 + u0);
  const float2 b1r = *(const float2*)(gb + 1536 + 512 + u0);
  const float2 b1h = *(const float2*)(gb + 1536 + 1024 + u0);
  const float2 hp = *(const float2*)(h0 + b * UNITS + u0);

  const float z0 = sigmoidf_(az.x + b0z.x + b1z.x);
  const float z1 = sigmoidf_(az.y + b0z.y + b1z.y);
  const float r0 = sigmoidf_(ar.x + b0r.x + b1r.x);
  const float r1 = sigmoidf_(ar.y + b0r.y + b1r.y);
  const float c0 = tanhf(ahx.x + b0h.x + r0 * (ahh.x + b1h.x));
  const float c1 = tanhf(ahx.y + b0h.y + r1 * (ahh.y + b1h.y));
  const float n0 = z0 * hp.x + (1.f - z0) * c0;
  const float n1 = z1 * hp.y + (1.f - z1) * c1;
  ws_dec[b * UNITS + u0]     = n0;
  ws_dec[b * UNITS + u0 + 1] = n1;
  out_dec[b * UNITS + u0]     = n0;
  out_dec[b * UNITS + u0 + 1] = n1;
}

// ---- K3: q & qw partial GEMM, k-split. grid (QKC, BATCH), 256 thr ----
// partial layout per (kc,b): [q(512) | qw(512)]
__global__ __launch_bounds__(256) void k_qq(
    const float* __restrict__ ws_dec, const float* __restrict__ Wsent,
    const float* __restrict__ Wword, float* __restrict__ qp)
{
  __shared__ float sdec[128];
  const int kc = blockIdx.x, b = blockIdx.y, t = threadIdx.x, u0 = 2 * t;
  const int k0 = kc * 128;
  if (t < 128) sdec[t] = ws_dec[b * UNITS + k0 + t];
  __syncthreads();

  float2 q = {0.f, 0.f}, w = {0.f, 0.f};
#pragma unroll 4
  for (int i = 0; i < 128; ++i) {
    const float d = sdec[i];
    const float2 a = *(const float2*)(Wsent + (size_t)(k0 + i) * UNITS + u0);
    const float2 c = *(const float2*)(Wword + (size_t)(k0 + i) * UNITS + u0);
    q.x = fmaf(d, a.x, q.x); q.y = fmaf(d, a.y, q.y);
    w.x = fmaf(d, c.x, w.x); w.y = fmaf(d, c.y, w.y);
  }
  float* o = qp + (size_t)(kc * BATCH + b) * 1024;
  *(float2*)(o + u0) = q;
  *(float2*)(o + 512 + u0) = w;
}

// ---- K4: finalize q/qw + sentence softmax + context + p_gen. grid (BATCH) ----
__global__ __launch_bounds__(256) void k_attn2(
    const float* __restrict__ qp, const float* __restrict__ encS,
    const float* __restrict__ ws_dec, const float* __restrict__ emb,
    const float* __restrict__ wctx, const float* __restrict__ whid,
    const float* __restrict__ winp,
    float* __restrict__ ws_qw, float* __restrict__ ws_alpha,
    float* __restrict__ ws_ctx, float* __restrict__ out_pgen)
{
  __shared__ float sq[UNITS], sctx[UNITS];
  __shared__ float sscore[NS], salpha[NS];
  __shared__ float sred[256];
  const int b = blockIdx.x, t = threadIdx.x, u0 = 2 * t;

  float2 q = {0.f, 0.f}, w = {0.f, 0.f};
#pragma unroll
  for (int c = 0; c < QKC; ++c) {
    const float* o = qp + (size_t)(c * BATCH + b) * 1024;
    const float2 qc = *(const float2*)(o + u0);
    const float2 wc = *(const float2*)(o + 512 + u0);
    q.x += qc.x; q.y += qc.y; w.x += wc.x; w.y += wc.y;
  }
  sq[u0] = q.x; sq[u0 + 1] = q.y;
  *(float2*)(ws_qw + b * UNITS + u0) = w;
  __syncthreads();

  const int wave = t >> 6, lane = t & 63;
  float qr[8];
#pragma unroll
  for (int j = 0; j < 8; ++j) qr[j] = sq[lane * 8 + j];
  for (int s = wave; s < NS; s += 4) {
    const float* base = encS + ((size_t)(b * NS + s)) * UNITS + lane * 8;
    const float4 v0 = *(const float4*)(base);
    const float4 v1 = *(const float4*)(base + 4);
    float acc = 0.f;
    acc = fmaf(v0.x, qr[0], acc); acc = fmaf(v0.y, qr[1], acc);
    acc = fmaf(v0.z, qr[2], acc); acc = fmaf(v0.w, qr[3], acc);
    acc = fmaf(v1.x, qr[4], acc); acc = fmaf(v1.y, qr[5], acc);
    acc = fmaf(v1.z, qr[6], acc); acc = fmaf(v1.w, qr[7], acc);
#pragma unroll
    for (int off = 32; off > 0; off >>= 1) acc += __shfl_down(acc, off);
    if (lane == 0) sscore[s] = acc;
  }
  __syncthreads();

  if (t < 32) {
    const float v = sscore[t];
    float m = v;
#pragma unroll
    for (int off = 16; off > 0; off >>= 1) m = fmaxf(m, __shfl_xor(m, off));
    const float e = __expf(v - m);
    float ssum = e;
#pragma unroll
    for (int off = 16; off > 0; off >>= 1) ssum += __shfl_xor(ssum, off);
    const float a = e / ssum;
    salpha[t] = a;
    ws_alpha[b * NS + t] = a;
  }
  __syncthreads();

  for (int u = t; u < UNITS; u += 256) {
    float c = 0.f;
#pragma unroll 4
    for (int s = 0; s < NS; ++s)
      c = fmaf(salpha[s], encS[((size_t)(b * NS + s)) * UNITS + u], c);
    sctx[u] = c;
    ws_ctx[b * UNITS + u] = c;
  }
  __syncthreads();

  float p = sctx[t] * wctx[t] + sctx[t + 256] * wctx[t + 256] +
            ws_dec[b * UNITS + t] * whid[t] +
            ws_dec[b * UNITS + 256 + t] * whid[t + 256] +
            emb[b * EMB + t] * winp[t];
  sred[t] = p;
  __syncthreads();
  for (int off = 128; off > 0; off >>= 1) {
    if (t < off) sred[t] += sred[t + off];
    __syncthreads();
  }
  if (t == 0) out_pgen[b] = sigmoidf_(sred[0]);
}

// ---- K5: hidden_t partial GEMM, k-split. grid (HKC, BATCH), 256 thr ----
__global__ __launch_bounds__(256) void k_ht(
    const float* __restrict__ ws_ctx, const float* __restrict__ ws_dec,
    const float* __restrict__ wdec, float* __restrict__ hp)
{
  __shared__ float scat[256];
  const int kc = blockIdx.x, b = blockIdx.y, t = threadIdx.x;
  const int k0 = kc * 256;
  const int k = k0 + t;
  scat[t] = (k < UNITS) ? ws_ctx[b * UNITS + k] : ws_dec[b * UNITS + k - UNITS];
  __syncthreads();

  float acc = 0.f;
#pragma unroll 4
  for (int i = 0; i < 256; ++i)
    acc = fmaf(scat[i], wdec[(size_t)(k0 + i) * 256 + t], acc);
  hp[(size_t)(kc * BATCH + b) * 256 + t] = acc;
}

// ---- K6: hidden_t finalize (tanh). grid (BATCH), 256 thr ----
__global__ __launch_bounds__(256) void k_ht_fin(
    const float* __restrict__ hp, float* __restrict__ ws_ht)
{
  const int b = blockIdx.x, t = threadIdx.x;
  float s = 0.f;
#pragma unroll
  for (int c = 0; c < HKC; ++c) s += hp[(size_t)(c * BATCH + b) * 256 + t];
  ws_ht[b * 256 + t] = tanhf(s);
}

// ---- Kernel C: gen exp(logits) -> out_gen (fp32) + fp32 rowsum atomics ----
// 1-D grid: bid&3 = row group (16 rows), bid>>2 = column block (512 cols).
// 8-deep register double-buffer keeps 8 global loads in flight per wave.
__global__ __launch_bounds__(256) void k_fc(
    const float* __restrict__ ws_ht, const float* __restrict__ fcW,
    const float* __restrict__ fcb, float* __restrict__ out_gen,
    float* __restrict__ ws_rowsum)
{
  __shared__ float sht[EMB * 16];  // [k][r] transposed: broadcast reads
  const int t = threadIdx.x;
  const int bid = blockIdx.x;
  const int g = bid & 3;
  const int cb = (bid >> 2) * 512;

#pragma unroll
  for (int i = 0; i < 16; ++i)
    sht[t * 16 + i] = ws_ht[(g * 16 + i) * EMB + t];
  __syncthreads();

  const int c0 = cb + 2 * t;
  float2 acc[16];
#pragma unroll
  for (int r = 0; r < 16; ++r) acc[r] = make_float2(0.f, 0.f);

  if (c0 < VOCAB) {
    const float* p = fcW + c0;
    float2 w[8];
#pragma unroll
    for (int j = 0; j < 8; ++j) w[j] = *(const float2*)(p + (size_t)j * VOCAB);

    for (int k = 0; k < EMB - 8; k += 8) {
      float2 wn[8];
#pragma unroll
      for (int j = 0; j < 8; ++j)
        wn[j] = *(const float2*)(p + (size_t)(k + 8 + j) * VOCAB);
#pragma unroll
      for (int j = 0; j < 8; ++j) {
        const float* hpk = sht + (k + j) * 16;
#pragma unroll
        for (int rg = 0; rg < 4; ++rg) {
          const float4 h4 = *(const float4*)(hpk + rg * 4);
          acc[rg * 4 + 0].x = fmaf(h4.x, w[j].x, acc[rg * 4 + 0].x);
          acc[rg * 4 + 0].y = fmaf(h4.x, w[j].y, acc[rg * 4 + 0].y);
          acc[rg * 4 + 1].x = fmaf(h4.y, w[j].x, acc[rg * 4 + 1].x);
          acc[rg * 4 + 1].y = fmaf(h4.y, w[j].y, acc[rg * 4 + 1].y);
          acc[rg * 4 + 2].x = fmaf(h4.z, w[j].x, acc[rg * 4 + 2].x);
          acc[rg * 4 + 2].y = fmaf(h4.z, w[j].y, acc[rg * 4 + 2].y);
          acc[rg * 4 + 3].x = fmaf(h4.w, w[j].x, acc[rg * 4 + 3].x);
          acc[rg * 4 + 3].y = fmaf(h4.w, w[j].y, acc[rg * 4 + 3].y);
        }
      }
#pragma unroll
      for (int j = 0; j < 8; ++j) w[j] = wn[j];
    }
    // tail batch: k = EMB-8
#pragma unroll
    for (int j = 0; j < 8; ++j) {
      const float* hpk = sht + (EMB - 8 + j) * 16;
#pragma unroll
      for (int rg = 0; rg < 4; ++rg) {
        const float4 h4 = *(const float4*)(hpk + rg * 4);
        acc[rg * 4 + 0].x = fmaf(h4.x, w[j].x, acc[rg * 4 + 0].x);
        acc[rg * 4 + 0].y = fmaf(h4.x, w[j].y, acc[rg * 4 + 0].y);
        acc[rg * 4 + 1].x = fmaf(h4.y, w[j].x, acc[rg * 4 + 1].x);
        acc[rg * 4 + 1].y = fmaf(h4.y, w[j].y, acc[rg * 4 + 1].y);
        acc[rg * 4 + 2].x = fmaf(h4.z, w[j].x, acc[rg * 4 + 2].x);
        acc[rg * 4 + 2].y = fmaf(h4.z, w[j].y, acc[rg * 4 + 2].y);
        acc[rg * 4 + 3].x = fmaf(h4.w, w[j].x, acc[rg * 4 + 3].x);
        acc[rg * 4 + 3].y = fmaf(h4.w, w[j].y, acc[rg * 4 + 3].y);
      }
    }

    const float2 bb = *(const float2*)(fcb + c0);
#pragma unroll
    for (int r = 0; r < 16; ++r) {
      acc[r].x = __expf(acc[r].x + bb.x);   // logits tiny; no max-shift needed
      acc[r].y = __expf(acc[r].y + bb.y);
      *(float2*)(out_gen + (size_t)(g * 16 + r) * EXT + c0) = acc[r];
    }
  }
  const int lane = t & 63;
#pragma unroll
  for (int r = 0; r < 16; ++r) {
    float s = (c0 < VOCAB) ? (acc[r].x + acc[r].y) : 0.f;
#pragma unroll
    for (int off = 32; off > 0; off >>= 1) s += __shfl_down(s, off);
    if (lane == 0) atomicAdd(ws_rowsum + g * 16 + r, s);
  }
}

// ---- Kernel D: word attention -> beta (fp32, ws), block per (b,s) ----
__global__ __launch_bounds__(256) void k_word(
    const float* __restrict__ ws_qw, const float* __restrict__ encW,
    const float* __restrict__ ws_alpha, float* __restrict__ ws_beta)
{
  __shared__ float sqw[UNITS];
  __shared__ float sscore[NW];
  const int bi = blockIdx.x;
  const int b = bi >> 5, s = bi & 31;
  const int t = threadIdx.x;
  sqw[t]       = ws_qw[b * UNITS + t];
  sqw[t + 256] = ws_qw[b * UNITS + 256 + t];
  __syncthreads();

  const int wave = t >> 6, lane = t & 63;
  float qr[8];
#pragma unroll
  for (int j = 0; j < 8; ++j) qr[j] = sqw[lane * 8 + j];
  const float* base = encW + ((size_t)(b * NS + s)) * NW * UNITS;
  for (int w = wave; w < NW; w += 4) {
    const float* row = base + w * UNITS + lane * 8;
    const float4 v0 = *(const float4*)(row);
    const float4 v1 = *(const float4*)(row + 4);
    float acc = 0.f;
    acc = fmaf(v0.x, qr[0], acc); acc = fmaf(v0.y, qr[1], acc);
    acc = fmaf(v0.z, qr[2], acc); acc = fmaf(v0.w, qr[3], acc);
    acc = fmaf(v1.x, qr[4], acc); acc = fmaf(v1.y, qr[5], acc);
    acc = fmaf(v1.z, qr[6], acc); acc = fmaf(v1.w, qr[7], acc);
#pragma unroll
    for (int off = 32; off > 0; off >>= 1) acc += __shfl_down(acc, off);
    if (lane == 0) sscore[w] = acc;
  }
  __syncthreads();

  if (t < 64) {
    const float v = (t < NW) ? sscore[t] : -1e30f;
    float m = v;
#pragma unroll
    for (int off = 32; off > 0; off >>= 1) m = fmaxf(m, __shfl_xor(m, off));
    const float e = (t < NW) ? __expf(v - m) : 0.f;
    float sum = e;
#pragma unroll
    for (int off = 32; off > 0; off >>= 1) sum += __shfl_xor(sum, off);
    if (t < NW)
      ws_beta[b * (NS * NW) + s * NW + t] = ws_alpha[b * NS + s] * e / sum;
  }
}

// ---- Kernel E: LDS-histogram scatter-add -> out_copy (block per (b, range)) --
__global__ __launch_bounds__(256) void k_copy(
    const int* __restrict__ nidx, const float* __restrict__ ws_beta,
    float* __restrict__ out_copy)
{
  __shared__ float shist[BINS_PER];
  const int q = blockIdx.x, b = blockIdx.y, t = threadIdx.x;
  const int base = q * BINS_PER;
  const int len = min(BINS_PER, EXT - base);

  for (int j = t; j < BINS_PER; j += 256) shist[j] = 0.f;
  __syncthreads();

  for (int e = t; e < NS * NW; e += 256) {
    const int rel = nidx[b * (NS * NW) + e] - base;
    if (rel >= 0 && rel < len) atomicAdd(shist + rel, ws_beta[b * (NS * NW) + e]);
  }
  __syncthreads();

  for (int j = t; j < len; j += 256)
    out_copy[(size_t)b * EXT + base + j] = shist[j];
}

// ------------- Kernel F: normalize out_gen in place + zero OOV pad -------------
__global__ __launch_bounds__(256) void k_final(
    const float* __restrict__ ws_rowsum, float* __restrict__ out_gen)
{
  const int i = blockIdx.x * 256 + threadIdx.x;
  if (i >= BATCH * EXT) return;
  const int b = i / EXT, c = i - b * EXT;
  float g = 0.f;
  if (c < VOCAB) g = out_gen[i] / ws_rowsum[b];
  out_gen[i] = g;
}

extern "C" void kernel_launch(void* const* d_in, const int* in_sizes, int n_in,
                              void* d_out, int out_size, void* d_ws, size_t ws_size,
                              hipStream_t stream)
{
  const float* emb   = (const float*)d_in[0];
  const float* h0    = (const float*)d_in[1];
  const float* encS  = (const float*)d_in[2];
  const float* encW  = (const float*)d_in[3];
  const int*   nidx  = (const int*)d_in[4];
  const float* Wx    = (const float*)d_in[6];
  const float* Wh    = (const float*)d_in[7];
  const float* gb    = (const float*)d_in[8];
  const float* Wsent = (const float*)d_in[9];
  const float* Wword = (const float*)d_in[10];
  const float* fcW   = (const float*)d_in[11];
  const float* fcb   = (const float*)d_in[12];
  const float* wctx  = (const float*)d_in[13];
  const float* whid  = (const float*)d_in[14];
  const float* wdec  = (const float*)d_in[15];
  const float* winp  = (const float*)d_in[16];

  float* ws        = (float*)d_ws;        // total ~4.1 MB
  float* ws_dec    = ws;                                  // 64*512
  float* ws_qw     = ws_dec + BATCH * UNITS;              // 64*512
  float* ws_alpha  = ws_qw + BATCH * UNITS;               // 64*32
  float* ws_ht     = ws_alpha + BATCH * NS;               // 64*256
  float* ws_rowsum = ws_ht + BATCH * EMB;                 // 64
  float* ws_beta   = ws_rowsum + BATCH;                   // 64*1600
  float* ws_ctx    = ws_beta + BATCH * NS * NW;           // 64*512
  float* ws_gp     = ws_ctx + BATCH * UNITS;              // 4*64*2048
  float* ws_qp     = ws_gp + GKC * BATCH * 2048;          // 4*64*1024
  float* ws_hp     = ws_qp + QKC * BATCH * 1024;          // 4*64*256

  float* out      = (float*)d_out;
  float* out_dec  = out;                                   // 64*512
  float* out_gen  = out + BATCH * UNITS;                   // 64*50100
  float* out_copy = out_gen + (size_t)BATCH * EXT;         // 64*50100
  float* out_pgen = out_copy + (size_t)BATCH * EXT;        // 64

  hipMemsetAsync(ws_rowsum, 0, BATCH * sizeof(float), stream);

  k_gru_part<<<dim3(GKC, BATCH), 256, 0, stream>>>(emb, h0, Wx, Wh, ws_gp);
  k_gru_fin<<<BATCH, 256, 0, stream>>>(ws_gp, gb, h0, ws_dec, out_dec);
  k_qq<<<dim3(QKC, BATCH), 256, 0, stream>>>(ws_dec, Wsent, Wword, ws_qp);
  k_attn2<<<BATCH, 256, 0, stream>>>(ws_qp, encS, ws_dec, emb, wctx, whid,
                                     winp, ws_qw, ws_alpha, ws_ctx, out_pgen);
  k_ht<<<dim3(HKC, BATCH), 256, 0, stream>>>(ws_ctx, ws_dec, wdec, ws_hp);
  k_ht_fin<<<BATCH, 256, 0, stream>>>(ws_hp, ws_ht);
  k_fc<<<dim3(((VOCAB + 511) / 512) * 4), 256, 0, stream>>>(ws_ht, fcW, fcb,
                                                            out_gen, ws_rowsum);
  k_word<<<BATCH * NS, 256, 0, stream>>>(ws_qw, encW, ws_alpha, ws_beta);
  k_copy<<<dim3(NQ, BATCH), 256, 0, stream>>>(nidx, ws_beta, out_copy);
  k_final<<<(BATCH * EXT + 255) / 256, 256, 0, stream>>>(ws_rowsum, out_gen);
}